// Round 4
// baseline (376.918 us; speedup 1.0000x reference)
//
#include <hip/hip_runtime.h>
#include <math.h>

#define N_   200
#define B_   512
#define K1_  100
#define K2_  50

// out layout: logp [512*2] | s1 [512*100] | s2 [512*50]
#define S1_OFF 1024
#define S2_OFF 52224

// workspace layout (bytes); requires ws_size >= 16,793,600
#define WS_H    0u           // 512*200*32 f = 13,107,200 B
#define WS_ES   13107200u    // 102400 f
#define WS_ED   13516800u    // 102400 f
#define WS_BITS 13926400u    // 716800 u32 = 2,867,200 B

__device__ __forceinline__ float lrelu(float v) { return v > 0.f ? v : 0.2f * v; }
__device__ __forceinline__ float sigm(float v)  { return 1.f / (1.f + __expf(-v)); }

__device__ __forceinline__ void bitonic_desc(float* key, int* idx, int n, int t) {
  for (int k = 2; k <= n; k <<= 1) {
    for (int j = k >> 1; j > 0; j >>= 1) {
      __syncthreads();
      int ixj = t ^ j;
      if (t < n && ixj > t) {
        float a = key[t], c = key[ixj];
        int ia = idx[t], ic = idx[ixj];
        bool gt = (a > c) || (a == c && ia < ic);
        if (((t & k) == 0) ? !gt : gt) {
          key[t] = c; key[ixj] = a; idx[t] = ic; idx[ixj] = ia;
        }
      }
    }
  }
  __syncthreads();
}

// ================= prep: h = X@W1 (+es/ed) and adj>0 bitmask =================
// blocks [0,3200): GEMM, 32 rows each (flattened M = 512*200 = 102400)
// blocks [3200,8800): bitmask, 128 words each (716800 words total)
__global__ __launch_bounds__(128) void prep(
    const float* __restrict__ x, const float* __restrict__ adj,
    const float* __restrict__ W1, const float* __restrict__ a1s,
    const float* __restrict__ a1d,
    float* __restrict__ hg, float* __restrict__ esg, float* __restrict__ edg,
    unsigned* __restrict__ bitsg)
{
  __shared__ __align__(16) float sX[32 * 200];
  const int t = threadIdx.x;
  const int blk = blockIdx.x;
  if (blk < 3200) {
    const int r0 = blk * 32;
    const float4* src = (const float4*)(x + (size_t)r0 * 200);
    float4* dst = (float4*)sX;
    #pragma unroll
    for (int i = 0; i < 13; ++i) {
      int idx = t + i * 128;
      if (idx < 1600) dst[idx] = src[idx];
    }
    __syncthreads();
    const int rl = t >> 2;          // row in tile 0..31
    const int dq = t & 3;           // dim octet 0..3 (dims dq*8..dq*8+8)
    const float4* W14 = (const float4*)W1;
    const float4* xr4 = (const float4*)(sX + rl * 200);
    float4 a0 = make_float4(0.f, 0.f, 0.f, 0.f);
    float4 a1 = make_float4(0.f, 0.f, 0.f, 0.f);
    for (int k4 = 0; k4 < 50; ++k4) {
      float4 xv = xr4[k4];
      #pragma unroll
      for (int kk = 0; kk < 4; ++kk) {
        int k = k4 * 4 + kk;
        float xs = (&xv.x)[kk];
        float4 w0 = W14[k * 8 + dq * 2];
        float4 w1 = W14[k * 8 + dq * 2 + 1];
        a0.x += xs * w0.x; a0.y += xs * w0.y; a0.z += xs * w0.z; a0.w += xs * w0.w;
        a1.x += xs * w1.x; a1.y += xs * w1.y; a1.z += xs * w1.z; a1.w += xs * w1.w;
      }
    }
    const int r = r0 + rl;
    float4* hg4 = (float4*)hg;
    hg4[r * 8 + dq * 2]     = a0;
    hg4[r * 8 + dq * 2 + 1] = a1;
    float4 s0 = *(const float4*)(a1s + dq * 8);
    float4 s1 = *(const float4*)(a1s + dq * 8 + 4);
    float4 d0 = *(const float4*)(a1d + dq * 8);
    float4 d1 = *(const float4*)(a1d + dq * 8 + 4);
    float pes = a0.x*s0.x + a0.y*s0.y + a0.z*s0.z + a0.w*s0.w
              + a1.x*s1.x + a1.y*s1.y + a1.z*s1.z + a1.w*s1.w;
    float ped = a0.x*d0.x + a0.y*d0.y + a0.z*d0.z + a0.w*d0.w
              + a1.x*d1.x + a1.y*d1.y + a1.z*d1.z + a1.w*d1.w;
    pes += __shfl_xor(pes, 1, 64); pes += __shfl_xor(pes, 2, 64);
    ped += __shfl_xor(ped, 1, 64); ped += __shfl_xor(ped, 2, 64);
    if (dq == 0) { esg[r] = pes; edg[r] = ped; }
  } else {
    const int wg = (blk - 3200) * 128 + t;      // < 716800
    const int row = wg / 7;
    const int w = wg - row * 7;
    const float* p = adj + (size_t)row * 200 + w * 32;
    unsigned m = 0u;
    const int lim = (w < 6) ? 32 : 8;
    for (int e = 0; e < lim; e += 4) {
      float4 v = *(const float4*)(p + e);
      m |= (unsigned)(v.x > 0.f) << e;
      m |= (unsigned)(v.y > 0.f) << (e + 1);
      m |= (unsigned)(v.z > 0.f) << (e + 2);
      m |= (unsigned)(v.w > 0.f) << (e + 3);
    }
    bitsg[wg] = m;
  }
}

// ================= main: GAT1 agg -> pool1 -> 2hop -> GAT2 -> pool2 -> head ==
// LDS map (bytes), total 50592 -> 3 blocks/CU:
//     0 : sH    25600  h(200x32); h2(100x32) phase E (rows 0..99)
// 25600 : sBITS  5600  adj>0 bits; sW2 (4096) aliases after phase D
// 31200 : sXK   12800  xk(100x32); xk2(50x32) phase F
// 44000 : sES     800
// 44800 : sED     800
// 45600 : sKey   1024
// 46624 : sIdx   1024  (sInv aliases after sel/val extracted)
// 47648 : sSel    400
// 48048 : sVal    400
// 48448 : sXV     512
// 48960 : sRed     32
// 48992 : sMask2 1600  100 x stride 4 u32
__global__ __launch_bounds__(256) void gnn_main(
    const float* __restrict__ hg, const float* __restrict__ esg,
    const float* __restrict__ edg, const unsigned* __restrict__ bitsg,
    const float* __restrict__ b1, const float* __restrict__ W2g,
    const float* __restrict__ a2s, const float* __restrict__ a2d,
    const float* __restrict__ b2,
    const float* __restrict__ pw1, const float* __restrict__ pw2,
    const float* __restrict__ fc1w, const float* __restrict__ fc1b,
    const float* __restrict__ fc2w, const float* __restrict__ fc2b,
    const float* __restrict__ fc3w, const float* __restrict__ fc3b,
    const float* __restrict__ bn4g, const float* __restrict__ bn4b,
    const float* __restrict__ bn5g, const float* __restrict__ bn5b,
    float* __restrict__ out)
{
  __shared__ __align__(16) char smem[50592];
  float*    sH    = (float*)smem;
  unsigned* sBITS = (unsigned*)(smem + 25600);
  float*    sW2   = (float*)(smem + 25600);
  float*    sXK   = (float*)(smem + 31200);
  float*    sES   = (float*)(smem + 44000);
  float*    sED   = (float*)(smem + 44800);
  float*    sKey  = (float*)(smem + 45600);
  int*      sIdx  = (int*)(smem + 46624);
  int*      sInv  = (int*)(smem + 46624);
  int*      sSel  = (int*)(smem + 47648);
  float*    sVal  = (float*)(smem + 48048);
  float*    sXV   = (float*)(smem + 48448);
  float*    sRed  = (float*)(smem + 48960);
  unsigned* sMask2= (unsigned*)(smem + 48992);

  const int t = threadIdx.x;
  const int b = blockIdx.x;

  // ---- load h, es, ed, bits (all coalesced) ----
  {
    const float4* hsrc = (const float4*)(hg + (size_t)b * 6400);
    float4* hdst = (float4*)sH;
    for (int i = t; i < 1600; i += 256) hdst[i] = hsrc[i];
    if (t < 50) {
      ((float4*)sES)[t] = ((const float4*)(esg + b * 200))[t];
      ((float4*)sED)[t] = ((const float4*)(edg + b * 200))[t];
    }
    const uint4* bsrc = (const uint4*)(bitsg + b * 1400);
    uint4* bdst = (uint4*)sBITS;
    for (int i = t; i < 350; i += 256) bdst[i] = bsrc[i];
  }
  __syncthreads();

  // esmax (safe softmax bound; leaky_relu monotone)
  {
    float v = (t < N_) ? sES[t] : -3.0e38f;
    #pragma unroll
    for (int off = 1; off < 64; off <<= 1) v = fmaxf(v, __shfl_xor(v, off, 64));
    if ((t & 63) == 0) sRed[t >> 6] = v;
  }
  __syncthreads();
  const float esmax = fmaxf(fmaxf(sRed[0], sRed[1]), fmaxf(sRed[2], sRed[3]));

  // ---- Phase B: GAT1 aggregate, results stay in registers ----
  const int wv = t >> 6, lane = t & 63;
  const int dg = lane >> 4, rg = lane & 15;
  float h1v[4][8]; float ssum1[4]; float edv1[4], Lv1[4];
  int rowc1[4]; bool val1[4];
  float b1c[8];
  *(float4*)&b1c[0] = *(const float4*)(b1 + dg * 8);
  *(float4*)&b1c[4] = *(const float4*)(b1 + dg * 8 + 4);
  {
    const int rbase = wv * 50;
    #pragma unroll
    for (int rr = 0; rr < 4; ++rr) {
      int rl = rg + 16 * rr;
      val1[rr] = rl < 50;
      rowc1[rr] = val1[rr] ? (rbase + rl) : 0;
      edv1[rr] = sED[rowc1[rr]];
      Lv1[rr]  = lrelu(edv1[rr] + esmax);
      ssum1[rr] = 0.f;
      #pragma unroll
      for (int u = 0; u < 8; ++u) h1v[rr][u] = 0.f;
    }
    for (int jw = 0; jw < 7; ++jw) {
      unsigned mw[4];
      #pragma unroll
      for (int rr = 0; rr < 4; ++rr) {
        mw[rr] = val1[rr] ? sBITS[rowc1[rr] * 7 + jw] : 0u;
        if (val1[rr] && (rowc1[rr] >> 5) == jw) mw[rr] |= 1u << (rowc1[rr] & 31);
      }
      const int cnt = (jw < 6) ? 32 : 8;
      for (int jj4 = 0; jj4 < cnt; jj4 += 4) {
        float4 esv = *(const float4*)&sES[jw * 32 + jj4];
        #pragma unroll
        for (int u = 0; u < 4; ++u) {
          int jj = jj4 + u;
          int j = jw * 32 + jj;
          float esj = (&esv.x)[u];
          float4 h0 = *(const float4*)&sH[j * 32 + dg * 8];
          float4 h1x = *(const float4*)&sH[j * 32 + dg * 8 + 4];
          #pragma unroll
          for (int rr = 0; rr < 4; ++rr) {
            float w = ((mw[rr] >> jj) & 1u) ? __expf(lrelu(edv1[rr] + esj) - Lv1[rr]) : 0.f;
            ssum1[rr] += w;
            h1v[rr][0] += w * h0.x;  h1v[rr][1] += w * h0.y;
            h1v[rr][2] += w * h0.z;  h1v[rr][3] += w * h0.w;
            h1v[rr][4] += w * h1x.x; h1v[rr][5] += w * h1x.y;
            h1v[rr][6] += w * h1x.z; h1v[rr][7] += w * h1x.w;
          }
        }
      }
    }
    #pragma unroll
    for (int rr = 0; rr < 4; ++rr) {
      float inv = 1.f / ssum1[rr];
      #pragma unroll
      for (int u = 0; u < 8; ++u) h1v[rr][u] = h1v[rr][u] * inv + b1c[u];
    }
  }

  // ---- Phase C: scores via shfl, sort, select, scatter xk ----
  {
    float npw = 0.f;
    #pragma unroll
    for (int d = 0; d < 32; ++d) npw += pw1[d] * pw1[d];
    npw = sqrtf(npw) + 1e-16f;
    float pwc[8];
    *(float4*)&pwc[0] = *(const float4*)(pw1 + dg * 8);
    *(float4*)&pwc[4] = *(const float4*)(pw1 + dg * 8 + 4);
    sKey[t] = -1.f; sIdx[t] = t;
    __syncthreads();
    #pragma unroll
    for (int rr = 0; rr < 4; ++rr) {
      float p = 0.f;
      #pragma unroll
      for (int u = 0; u < 8; ++u) p += h1v[rr][u] * pwc[u];
      p += __shfl_xor(p, 16, 64);
      p += __shfl_xor(p, 32, 64);
      if (dg == 0 && val1[rr]) sKey[rowc1[rr]] = sigm(p / npw);
    }
  }
  bitonic_desc(sKey, sIdx, 256, t);
  if (t < K1_) {
    out[S1_OFF + b * K1_ + t] = sKey[t];
    sVal[t] = sKey[t]; sSel[t] = sIdx[t];
  }
  __syncthreads();
  if (t < 200) sInv[t] = -1;
  __syncthreads();
  if (t < K1_) sInv[sSel[t]] = t;
  __syncthreads();
  #pragma unroll
  for (int rr = 0; rr < 4; ++rr) {
    if (val1[rr]) {
      int rk = sInv[rowc1[rr]];
      if (rk >= 0) {
        float vm = sVal[rk];
        float4 o0 = make_float4(h1v[rr][0]*vm, h1v[rr][1]*vm, h1v[rr][2]*vm, h1v[rr][3]*vm);
        float4 o1 = make_float4(h1v[rr][4]*vm, h1v[rr][5]*vm, h1v[rr][6]*vm, h1v[rr][7]*vm);
        *(float4*)&sXK[rk * 32 + dg * 8]     = o0;
        *(float4*)&sXK[rk * 32 + dg * 8 + 4] = o1;
      }
    }
  }
  __syncthreads();

  // x1 pool (t<32) runs concurrently with phase D mask build (disjoint LDS)
  if (t < 32) {
    float m = -3.0e38f, s = 0.f;
    for (int r = 0; r < K1_; ++r) { float v = sXK[r * 32 + t]; m = fmaxf(m, v); s += v; }
    sXV[t] = m; sXV[32 + t] = s / 100.f;
  }

  // ---- Phase D: M=(A1+I) rows, then 2-hop reachability ----
  if (t < K1_) {
    int gi = sSel[t];
    unsigned bt[7];
    #pragma unroll
    for (int w = 0; w < 7; ++w) bt[w] = sBITS[gi * 7 + w];
    #pragma unroll
    for (int w = 0; w < 4; ++w) {
      unsigned m = 0;
      const int lim = (w < 3) ? 32 : 4;
      for (int jj = 0; jj < lim; ++jj) {
        int j = w * 32 + jj;
        int gj = sSel[j];
        unsigned bit = (bt[gj >> 5] >> (gj & 31)) & 1u;
        if (j == t) bit = 1u;
        m |= bit << jj;
      }
      sMask2[t * 4 + w] = m;
    }
  }
  __syncthreads();
  {
    unsigned pr0 = 0, pr1 = 0, pr2 = 0, pr3 = 0;
    unsigned ow0 = 0, ow1 = 0, ow2 = 0, ow3 = 0;
    if (t < K1_) {
      ow0 = sMask2[t * 4 + 0]; ow1 = sMask2[t * 4 + 1];
      ow2 = sMask2[t * 4 + 2]; ow3 = sMask2[t * 4 + 3];
    }
    for (int k = 0; k < K1_; ++k) {
      uint4 mk = *(const uint4*)&sMask2[k * 4];
      unsigned bit = (k < 32) ? (ow0 >> k) : (k < 64) ? (ow1 >> (k - 32))
                   : (k < 96) ? (ow2 >> (k - 64)) : (ow3 >> (k - 96));
      unsigned sel = (bit & 1u) ? 0xFFFFFFFFu : 0u;
      pr0 |= mk.x & sel; pr1 |= mk.y & sel; pr2 |= mk.z & sel; pr3 |= mk.w & sel;
    }
    __syncthreads();
    if (t < K1_) {
      sMask2[t * 4 + 0] = pr0; sMask2[t * 4 + 1] = pr1;
      sMask2[t * 4 + 2] = pr2; sMask2[t * 4 + 3] = pr3;
    }
  }
  __syncthreads();

  // ---- Phase E: GAT2 (GEMM + aggregate in registers) ----
  for (int i = t; i < 1024; i += 256) sW2[i] = W2g[i];   // sBITS dead now
  __syncthreads();
  if (t < K1_) {
    float acc[32];
    #pragma unroll
    for (int d = 0; d < 32; ++d) acc[d] = 0.f;
    const float4* xk4 = (const float4*)(sXK + t * 32);
    for (int k4 = 0; k4 < 8; ++k4) {
      float4 xv = xk4[k4];
      #pragma unroll
      for (int kk = 0; kk < 4; ++kk) {
        float xs = (&xv.x)[kk];
        const float* wr = &sW2[(k4 * 4 + kk) * 32];
        #pragma unroll
        for (int d = 0; d < 32; ++d) acc[d] += xs * wr[d];
      }
    }
    float es = 0.f, ed = 0.f;
    #pragma unroll
    for (int d = 0; d < 32; ++d) { es += acc[d] * a2s[d]; ed += acc[d] * a2d[d]; }
    sES[t] = es; sED[t] = ed;
    #pragma unroll
    for (int d = 0; d < 32; d += 4)
      *(float4*)&sH[t * 32 + d] = make_float4(acc[d], acc[d+1], acc[d+2], acc[d+3]);
  }
  __syncthreads();
  {
    float v = (t < K1_) ? sES[t] : -3.0e38f;
    #pragma unroll
    for (int off = 1; off < 64; off <<= 1) v = fmaxf(v, __shfl_xor(v, off, 64));
    if ((t & 63) == 0) sRed[t >> 6] = v;
  }
  __syncthreads();
  const float esm2 = fmaxf(fmaxf(sRed[0], sRed[1]), fmaxf(sRed[2], sRed[3]));

  float h2v[2][8]; float ssum2[2]; float edv2[2], Lv2[2];
  int rowc2[2]; bool val2[2];
  float b2c[8];
  *(float4*)&b2c[0] = *(const float4*)(b2 + dg * 8);
  *(float4*)&b2c[4] = *(const float4*)(b2 + dg * 8 + 4);
  {
    const int rbase = wv * 25;
    #pragma unroll
    for (int rr = 0; rr < 2; ++rr) {
      int rl = rg + 16 * rr;
      val2[rr] = rl < 25;
      rowc2[rr] = val2[rr] ? (rbase + rl) : 0;
      edv2[rr] = sED[rowc2[rr]];
      Lv2[rr]  = lrelu(edv2[rr] + esm2);
      ssum2[rr] = 0.f;
      #pragma unroll
      for (int u = 0; u < 8; ++u) h2v[rr][u] = 0.f;
    }
    for (int jw = 0; jw < 4; ++jw) {
      unsigned mw[2];
      #pragma unroll
      for (int rr = 0; rr < 2; ++rr)
        mw[rr] = val2[rr] ? sMask2[rowc2[rr] * 4 + jw] : 0u;   // diag already set
      const int cnt = (jw < 3) ? 32 : 4;
      for (int jj4 = 0; jj4 < cnt; jj4 += 4) {
        float4 esv = *(const float4*)&sES[jw * 32 + jj4];
        #pragma unroll
        for (int u = 0; u < 4; ++u) {
          int jj = jj4 + u;
          int j = jw * 32 + jj;
          float esj = (&esv.x)[u];
          float4 h0 = *(const float4*)&sH[j * 32 + dg * 8];
          float4 h1x = *(const float4*)&sH[j * 32 + dg * 8 + 4];
          #pragma unroll
          for (int rr = 0; rr < 2; ++rr) {
            float w = ((mw[rr] >> jj) & 1u) ? __expf(lrelu(edv2[rr] + esj) - Lv2[rr]) : 0.f;
            ssum2[rr] += w;
            h2v[rr][0] += w * h0.x;  h2v[rr][1] += w * h0.y;
            h2v[rr][2] += w * h0.z;  h2v[rr][3] += w * h0.w;
            h2v[rr][4] += w * h1x.x; h2v[rr][5] += w * h1x.y;
            h2v[rr][6] += w * h1x.z; h2v[rr][7] += w * h1x.w;
          }
        }
      }
    }
    #pragma unroll
    for (int rr = 0; rr < 2; ++rr) {
      float inv = 1.f / ssum2[rr];
      #pragma unroll
      for (int u = 0; u < 8; ++u) h2v[rr][u] = h2v[rr][u] * inv + b2c[u];
    }
  }

  // ---- Phase F: pool2 ----
  {
    float npw = 0.f;
    #pragma unroll
    for (int d = 0; d < 32; ++d) npw += pw2[d] * pw2[d];
    npw = sqrtf(npw) + 1e-16f;
    float pwc[8];
    *(float4*)&pwc[0] = *(const float4*)(pw2 + dg * 8);
    *(float4*)&pwc[4] = *(const float4*)(pw2 + dg * 8 + 4);
    if (t < 128) { sKey[t] = -1.f; sIdx[t] = t; }
    __syncthreads();
    #pragma unroll
    for (int rr = 0; rr < 2; ++rr) {
      float p = 0.f;
      #pragma unroll
      for (int u = 0; u < 8; ++u) p += h2v[rr][u] * pwc[u];
      p += __shfl_xor(p, 16, 64);
      p += __shfl_xor(p, 32, 64);
      if (dg == 0 && val2[rr]) sKey[rowc2[rr]] = sigm(p / npw);
    }
  }
  bitonic_desc(sKey, sIdx, 128, t);
  if (t < K2_) {
    out[S2_OFF + b * K2_ + t] = sKey[t];
    sVal[t] = sKey[t]; sSel[t] = sIdx[t];
  }
  __syncthreads();
  if (t < K1_) sInv[t] = -1;
  __syncthreads();
  if (t < K2_) sInv[sSel[t]] = t;
  __syncthreads();
  #pragma unroll
  for (int rr = 0; rr < 2; ++rr) {
    if (val2[rr]) {
      int rk = sInv[rowc2[rr]];
      if (rk >= 0) {
        float vm = sVal[rk];
        float4 o0 = make_float4(h2v[rr][0]*vm, h2v[rr][1]*vm, h2v[rr][2]*vm, h2v[rr][3]*vm);
        float4 o1 = make_float4(h2v[rr][4]*vm, h2v[rr][5]*vm, h2v[rr][6]*vm, h2v[rr][7]*vm);
        *(float4*)&sXK[rk * 32 + dg * 8]     = o0;
        *(float4*)&sXK[rk * 32 + dg * 8 + 4] = o1;
      }
    }
  }
  __syncthreads();
  if (t < 32) {
    float m = -3.0e38f, s = 0.f;
    for (int r = 0; r < K2_; ++r) { float v = sXK[r * 32 + t]; m = fmaxf(m, v); s += v; }
    sXV[64 + t] = m; sXV[96 + t] = s / 50.f;
  }
  __syncthreads();

  // ---- Phase G: MLP head ----
  const float RS = 0.99999500003749969f;   // 1/sqrt(1+1e-5)
  if (t < 32) {
    float z = fc1b[t];
    for (int k = 0; k < 128; ++k) z += sXV[k] * fc1w[k * 32 + t];
    z = fmaxf(z, 0.f);
    z = bn4g[t] * z * RS + bn4b[t];
    sKey[t] = z;
  }
  __syncthreads();
  if (t < 8) {
    float z = fc2b[t];
    for (int k = 0; k < 32; ++k) z += sKey[k] * fc2w[k * 8 + t];
    z = fmaxf(z, 0.f);
    z = bn5g[t] * z * RS + bn5b[t];
    sKey[32 + t] = z;
  }
  __syncthreads();
  if (t < 2) {
    float z = fc3b[t];
    for (int k = 0; k < 8; ++k) z += sKey[32 + k] * fc3w[k * 2 + t];
    sKey[40 + t] = z;
  }
  __syncthreads();
  if (t < 2) {
    float z0 = sKey[40], z1 = sKey[41];
    float m = fmaxf(z0, z1);
    float lse = m + logf(__expf(z0 - m) + __expf(z1 - m));
    out[b * 2 + t] = sKey[40 + t] - lse;
  }
}

extern "C" void kernel_launch(void* const* d_in, const int* in_sizes, int n_in,
                              void* d_out, int out_size, void* d_ws, size_t ws_size,
                              hipStream_t stream) {
  (void)in_sizes; (void)n_in; (void)ws_size; (void)out_size;
  const float* x    = (const float*)d_in[0];
  const float* adj  = (const float*)d_in[1];
  const float* W1   = (const float*)d_in[2];
  const float* a1s  = (const float*)d_in[3];
  const float* a1d  = (const float*)d_in[4];
  const float* b1   = (const float*)d_in[5];
  const float* W2   = (const float*)d_in[6];
  const float* a2s  = (const float*)d_in[7];
  const float* a2d  = (const float*)d_in[8];
  const float* b2   = (const float*)d_in[9];
  const float* pw1  = (const float*)d_in[10];
  const float* pw2  = (const float*)d_in[11];
  const float* fc1w = (const float*)d_in[12];
  const float* fc1b = (const float*)d_in[13];
  const float* fc2w = (const float*)d_in[14];
  const float* fc2b = (const float*)d_in[15];
  const float* fc3w = (const float*)d_in[16];
  const float* fc3b = (const float*)d_in[17];
  const float* bn4g = (const float*)d_in[18];
  const float* bn4b = (const float*)d_in[19];
  const float* bn5g = (const float*)d_in[20];
  const float* bn5b = (const float*)d_in[21];

  char* ws = (char*)d_ws;
  float*    hg    = (float*)(ws + WS_H);
  float*    esg   = (float*)(ws + WS_ES);
  float*    edg   = (float*)(ws + WS_ED);
  unsigned* bitsg = (unsigned*)(ws + WS_BITS);

  prep<<<8800, 128, 0, stream>>>(x, adj, W1, a1s, a1d, hg, esg, edg, bitsg);
  gnn_main<<<B_, 256, 0, stream>>>(hg, esg, edg, bitsg,
                                   b1, W2, a2s, a2d, b2, pw1, pw2,
                                   fc1w, fc1b, fc2w, fc2b, fc3w, fc3b,
                                   bn4g, bn4b, bn5g, bn5b, (float*)d_out);
}